// Round 3
// baseline (376.181 us; speedup 1.0000x reference)
//
#include <hip/hip_runtime.h>
#include <math.h>

#define NROWS 4096
#define EDIM  1024
#define KNOISE 50
#define KTOT  51
#define NORM_TERM 9.0f
#define NSLOTS 256
#define RPW 13   // rows per wave (wave 3 padded with a dup, term masked)
#define PF  4    // rotating prefetch depth (rows in flight per wave)

// One block per row n, 4 waves. Wave w owns k in [13w, 13w+13) (k=51 is a
// masked dup). Structure for max load duty cycle:
//   - all 13 gather indices resolved up front into SGPRs (readfirstlane)
//   - main loop is a pure load+FMA stream with a 4-row rotating register
//     buffer: consume row j (16 fma) then immediately issue row j+4's loads
//   - per-lane partials dot[13]; ALL butterflies + exp/log deferred to tail
__global__ __launch_bounds__(256) void nce_main(
    const float* __restrict__ input,
    const int*   __restrict__ target,
    const int*   __restrict__ noise_samples,
    const float* __restrict__ noise,
    const float* __restrict__ weight,
    const float* __restrict__ bias,
    float*       __restrict__ partial)
{
    const int n    = blockIdx.x;
    const int tid  = threadIdx.x;
    const int wave = tid >> 6;
    const int lane = tid & 63;

    const float4* inrow = (const float4*)(input + (size_t)n * EDIM);
    float4 inv[4];
#pragma unroll
    for (int p = 0; p < 4; ++p)
        inv[p] = inrow[p * 64 + lane];

    const int start = wave * RPW;

    // ---- resolve all gather indices up front (uniform -> SGPR) ----
    int idx[RPW];
#pragma unroll
    for (int j = 0; j < RPW; ++j) {
        const int kk = start + j;
        const int kc = (kk < KTOT) ? kk : start;           // pad: dup row
        int v = (kc == 0) ? target[n] : noise_samples[n * KNOISE + kc - 1];
        idx[j] = __builtin_amdgcn_readfirstlane(v);
    }

    // ---- pure load+FMA stream with rotating 4-row prefetch buffer ----
    float dot[RPW];
#pragma unroll
    for (int j = 0; j < RPW; ++j) dot[j] = 0.0f;

    float4 buf[PF][4];
#pragma unroll
    for (int j = 0; j < PF; ++j) {
        const float4* wrow = (const float4*)(weight + (size_t)idx[j] * EDIM);
#pragma unroll
        for (int p = 0; p < 4; ++p)
            buf[j][p] = wrow[p * 64 + lane];
    }

#pragma unroll
    for (int j = 0; j < RPW; ++j) {
        const int s = j % PF;
#pragma unroll
        for (int p = 0; p < 4; ++p) {
            dot[j] = fmaf(inv[p].x, buf[s][p].x, dot[j]);
            dot[j] = fmaf(inv[p].y, buf[s][p].y, dot[j]);
            dot[j] = fmaf(inv[p].z, buf[s][p].z, dot[j]);
            dot[j] = fmaf(inv[p].w, buf[s][p].w, dot[j]);
        }
        if (j + PF < RPW) {
            const float4* wrow = (const float4*)(weight + (size_t)idx[j + PF] * EDIM);
#pragma unroll
            for (int p = 0; p < 4; ++p)
                buf[s][p] = wrow[p * 64 + lane];
        }
    }

    // ---- deferred reductions: 13 butterflies, interleaved (DS-pipelined) ----
#pragma unroll
    for (int off = 32; off > 0; off >>= 1) {
#pragma unroll
        for (int j = 0; j < RPW; ++j)
            dot[j] += __shfl_xor(dot[j], off, 64);
    }

    // ---- deferred term math (uniform across lanes) ----
    float acc = 0.0f;
#pragma unroll
    for (int j = 0; j < RPW; ++j) {
        const int kk = start + j;
        if (kk < KTOT) {   // wave-uniform guard (masks wave 3's dup row)
            const float bz = bias[idx[j]];
            const float cz = (float)KNOISE * noise[idx[j]];
            const float p  = __expf(dot[j] + bz - NORM_TERM);
            const float num = (kk == 0) ? p : cz;
            acc += __logf(num / (p + cz));
        }
    }

    // ---- block reduce (acc is lane-uniform within each wave) ----
    __shared__ float warr[4];
    if (lane == 0) warr[wave] = acc;
    __syncthreads();
    if (tid == 0) {
        const float s = warr[0] + warr[1] + warr[2] + warr[3];
        atomicAdd(&partial[n & (NSLOTS - 1)], -s * (1.0f / (float)NROWS));
    }
}

__global__ __launch_bounds__(64) void nce_finish(const float* __restrict__ partial,
                                                 float* __restrict__ out)
{
    const int lane = threadIdx.x;
    float v = partial[lane] + partial[lane + 64] + partial[lane + 128] + partial[lane + 192];
#pragma unroll
    for (int off = 32; off > 0; off >>= 1)
        v += __shfl_xor(v, off, 64);
    if (lane == 0) out[0] = v;
}

extern "C" void kernel_launch(void* const* d_in, const int* in_sizes, int n_in,
                              void* d_out, int out_size, void* d_ws, size_t ws_size,
                              hipStream_t stream) {
    const float* input         = (const float*)d_in[0];
    const int*   target        = (const int*)  d_in[1];
    const int*   noise_samples = (const int*)  d_in[2];
    const float* noise         = (const float*)d_in[3];
    const float* weight        = (const float*)d_in[4];
    const float* bias          = (const float*)d_in[5];
    float*       out           = (float*)d_out;
    float*       partial       = (float*)d_ws;   // 256 f32 slots

    hipMemsetAsync(partial, 0, NSLOTS * sizeof(float), stream);

    nce_main<<<NROWS, 256, 0, stream>>>(
        input, target, noise_samples, noise, weight, bias, partial);
    nce_finish<<<1, 64, 0, stream>>>(partial, out);
}

// Round 4
// 369.072 us; speedup vs baseline: 1.0193x; 1.0193x over previous
//
#include <hip/hip_runtime.h>
#include <hip/hip_fp16.h>
#include <math.h>

#define NROWS 4096
#define EDIM  1024
#define V     50257
#define KNOISE 50
#define KTOT  51
#define NORM_TERM 9.0f
#define NSLOTS 256

// ---------------- fp16 weight conversion (streaming, per call) --------------
__global__ __launch_bounds__(256) void convert_weight(
    const float* __restrict__ w, __half* __restrict__ wh)
{
    const int total8 = V * EDIM / 8;          // 6,432,896 groups of 8
    int i = blockIdx.x * blockDim.x + threadIdx.x;
    const int stride = gridDim.x * blockDim.x;
    for (; i < total8; i += stride) {
        const float4* p = (const float4*)w + 2 * (size_t)i;
        float4 a = p[0], b = p[1];
        union { uint4 u; __half2 h[4]; } o;
        o.h[0] = __floats2half2_rn(a.x, a.y);
        o.h[1] = __floats2half2_rn(a.z, a.w);
        o.h[2] = __floats2half2_rn(b.x, b.y);
        o.h[3] = __floats2half2_rn(b.z, b.w);
        ((uint4*)wh)[i] = o.u;
    }
}

// ---------------- fp16 gather main kernel -----------------------------------
// Lane fragment layout: chunk c = p*64+lane covers elements [8c, 8c+8).
// Per gathered row: 2 uint4 loads/lane (2 KB/row). Batch B rows -> 2B loads
// in flight; all reductions/transcendentals deferred to after the loads.
template<int B>
__device__ __forceinline__ void process_batch(
    int n, int lane, int k0,
    const int*   __restrict__ target,
    const int*   __restrict__ noise_samples,
    const float* __restrict__ noise,
    const __half* __restrict__ wh,
    const float* __restrict__ bias,
    const float inf[2][8],
    float& acc)
{
    int idx[B];
#pragma unroll
    for (int i = 0; i < B; ++i) {
        const int kk = k0 + i;
        const int kc = (kk < KTOT) ? kk : 0;          // pad -> target row (masked)
        idx[i] = (kc == 0) ? target[n] : noise_samples[n * KNOISE + kc - 1];
    }
    float bz[B], cz[B];
#pragma unroll
    for (int i = 0; i < B; ++i) {
        bz[i] = bias[idx[i]];
        cz[i] = (float)KNOISE * noise[idx[i]];
    }
    uint4 c[B][2];
#pragma unroll
    for (int i = 0; i < B; ++i) {
        const uint4* wrow = (const uint4*)(wh + (size_t)idx[i] * EDIM);
        c[i][0] = wrow[lane];
        c[i][1] = wrow[64 + lane];
    }
    float dot[B];
#pragma unroll
    for (int i = 0; i < B; ++i) dot[i] = 0.f;
#pragma unroll
    for (int i = 0; i < B; ++i) {
#pragma unroll
        for (int p = 0; p < 2; ++p) {
            const __half2* h = (const __half2*)&c[i][p];
#pragma unroll
            for (int q = 0; q < 4; ++q) {
                const float2 f = __half22float2(h[q]);
                dot[i] = fmaf(inf[p][2 * q],     f.x, dot[i]);
                dot[i] = fmaf(inf[p][2 * q + 1], f.y, dot[i]);
            }
        }
    }
#pragma unroll
    for (int off = 32; off > 0; off >>= 1) {
#pragma unroll
        for (int i = 0; i < B; ++i)
            dot[i] += __shfl_xor(dot[i], off, 64);
    }
#pragma unroll
    for (int i = 0; i < B; ++i) {
        const int kk = k0 + i;
        if (kk < KTOT) {                               // wave-uniform guard
            const float p   = __expf(dot[i] + bz[i] - NORM_TERM);
            const float num = (kk == 0) ? p : cz[i];
            acc += __logf(num / (p + cz[i]));
        }
    }
}

__global__ __launch_bounds__(256) void nce_main_h(
    const float* __restrict__ input,
    const int*   __restrict__ target,
    const int*   __restrict__ noise_samples,
    const float* __restrict__ noise,
    const __half* __restrict__ wh,
    const float* __restrict__ bias,
    float*       __restrict__ partial)
{
    const int n    = blockIdx.x;
    const int tid  = threadIdx.x;
    const int wave = tid >> 6;
    const int lane = tid & 63;

    const float4* inrow = (const float4*)(input + (size_t)n * EDIM);
    float inf[2][8];
#pragma unroll
    for (int p = 0; p < 2; ++p) {
        const float4 a = inrow[p * 128 + 2 * lane];
        const float4 b = inrow[p * 128 + 2 * lane + 1];
        inf[p][0] = a.x; inf[p][1] = a.y; inf[p][2] = a.z; inf[p][3] = a.w;
        inf[p][4] = b.x; inf[p][5] = b.y; inf[p][6] = b.z; inf[p][7] = b.w;
    }

    const int start = wave * 13;
    float acc = 0.f;
    process_batch<8>(n, lane, start,     target, noise_samples, noise, wh, bias, inf, acc);
    process_batch<5>(n, lane, start + 8, target, noise_samples, noise, wh, bias, inf, acc);

    __shared__ float warr[4];
    if (lane == 0) warr[wave] = acc;
    __syncthreads();
    if (tid == 0) {
        const float s = warr[0] + warr[1] + warr[2] + warr[3];
        atomicAdd(&partial[n & (NSLOTS - 1)], -s * (1.0f / (float)NROWS));
    }
}

// ---------------- f32 fallback (R2 structure) if ws too small ---------------
__global__ __launch_bounds__(256) void nce_main_f32(
    const float* __restrict__ input,
    const int*   __restrict__ target,
    const int*   __restrict__ noise_samples,
    const float* __restrict__ noise,
    const float* __restrict__ weight,
    const float* __restrict__ bias,
    float*       __restrict__ partial)
{
    const int n    = blockIdx.x;
    const int tid  = threadIdx.x;
    const int wave = tid >> 6;
    const int lane = tid & 63;

    const float4* inrow = (const float4*)(input + (size_t)n * EDIM);
    float4 inv[4];
#pragma unroll
    for (int p = 0; p < 4; ++p)
        inv[p] = inrow[p * 64 + lane];

    const int start = wave * 13;
    const int end   = (start + 13 < KTOT) ? start + 13 : KTOT;

    float acc = 0.0f;
    int k = start;
    for (; k + 4 <= end; k += 4) {
        int idx[4];
#pragma unroll
        for (int i = 0; i < 4; ++i) {
            const int kk = k + i;
            idx[i] = (kk == 0) ? target[n] : noise_samples[n * KNOISE + kk - 1];
        }
        float bz[4], cz[4];
#pragma unroll
        for (int i = 0; i < 4; ++i) {
            bz[i] = bias[idx[i]];
            cz[i] = (float)KNOISE * noise[idx[i]];
        }
        float4 wr[4][4];
#pragma unroll
        for (int i = 0; i < 4; ++i) {
            const float4* wrow = (const float4*)(weight + (size_t)idx[i] * EDIM);
#pragma unroll
            for (int p = 0; p < 4; ++p)
                wr[i][p] = wrow[p * 64 + lane];
        }
        float dot[4] = {0.f, 0.f, 0.f, 0.f};
#pragma unroll
        for (int i = 0; i < 4; ++i) {
#pragma unroll
            for (int p = 0; p < 4; ++p) {
                dot[i] = fmaf(inv[p].x, wr[i][p].x, dot[i]);
                dot[i] = fmaf(inv[p].y, wr[i][p].y, dot[i]);
                dot[i] = fmaf(inv[p].z, wr[i][p].z, dot[i]);
                dot[i] = fmaf(inv[p].w, wr[i][p].w, dot[i]);
            }
        }
#pragma unroll
        for (int off = 32; off > 0; off >>= 1) {
#pragma unroll
            for (int i = 0; i < 4; ++i)
                dot[i] += __shfl_xor(dot[i], off, 64);
        }
#pragma unroll
        for (int i = 0; i < 4; ++i) {
            const float p   = __expf(dot[i] + bz[i] - NORM_TERM);
            const float num = (k + i == 0) ? p : cz[i];
            acc += __logf(num / (p + cz[i]));
        }
    }
    for (; k < end; ++k) {
        const int idx = (k == 0) ? target[n] : noise_samples[n * KNOISE + k - 1];
        const float bz = bias[idx];
        const float cz = (float)KNOISE * noise[idx];
        const float4* wrow = (const float4*)(weight + (size_t)idx * EDIM);
        float dot = 0.f;
#pragma unroll
        for (int p = 0; p < 4; ++p) {
            float4 w = wrow[p * 64 + lane];
            dot = fmaf(inv[p].x, w.x, dot);
            dot = fmaf(inv[p].y, w.y, dot);
            dot = fmaf(inv[p].z, w.z, dot);
            dot = fmaf(inv[p].w, w.w, dot);
        }
#pragma unroll
        for (int off = 32; off > 0; off >>= 1)
            dot += __shfl_xor(dot, off, 64);
        const float p   = __expf(dot + bz - NORM_TERM);
        const float num = (k == 0) ? p : cz;
        acc += __logf(num / (p + cz));
    }

    __shared__ float warr[4];
    if (lane == 0) warr[wave] = acc;
    __syncthreads();
    if (tid == 0) {
        const float s = warr[0] + warr[1] + warr[2] + warr[3];
        atomicAdd(&partial[n & (NSLOTS - 1)], -s * (1.0f / (float)NROWS));
    }
}

__global__ __launch_bounds__(64) void nce_finish(const float* __restrict__ partial,
                                                 float* __restrict__ out)
{
    const int lane = threadIdx.x;
    float v = partial[lane] + partial[lane + 64] + partial[lane + 128] + partial[lane + 192];
#pragma unroll
    for (int off = 32; off > 0; off >>= 1)
        v += __shfl_xor(v, off, 64);
    if (lane == 0) out[0] = v;
}

extern "C" void kernel_launch(void* const* d_in, const int* in_sizes, int n_in,
                              void* d_out, int out_size, void* d_ws, size_t ws_size,
                              hipStream_t stream) {
    const float* input         = (const float*)d_in[0];
    const int*   target        = (const int*)  d_in[1];
    const int*   noise_samples = (const int*)  d_in[2];
    const float* noise         = (const float*)d_in[3];
    const float* weight        = (const float*)d_in[4];
    const float* bias          = (const float*)d_in[5];
    float*       out           = (float*)d_out;
    float*       partial       = (float*)d_ws;   // 256 f32 slots at ws[0]

    hipMemsetAsync(partial, 0, NSLOTS * sizeof(float), stream);

    const size_t need = 1024 + (size_t)V * EDIM * sizeof(__half);  // ~103 MB
    if (ws_size >= need) {
        __half* wh = (__half*)((char*)d_ws + 1024);
        convert_weight<<<4096, 256, 0, stream>>>(weight, wh);
        nce_main_h<<<NROWS, 256, 0, stream>>>(
            input, target, noise_samples, noise, wh, bias, partial);
    } else {
        nce_main_f32<<<NROWS, 256, 0, stream>>>(
            input, target, noise_samples, noise, weight, bias, partial);
    }
    nce_finish<<<1, 64, 0, stream>>>(partial, out);
}

// Round 5
// 344.541 us; speedup vs baseline: 1.0918x; 1.0712x over previous
//
#include <hip/hip_runtime.h>
#include <math.h>

#define NROWS 4096
#define EDIM  1024
#define V     50257
#define KNOISE 50
#define KTOT  51
#define NORM_TERM 9.0f
#define NSLOTS 256
#define RPW   13          // rows per wave (wave 3 has one masked dup)
#define WSCALE     64.0f  // pre-scale so |w*64| in [~0.06, 6.4] -> e4m3 normal range
#define INV_WSCALE (1.0f / 64.0f)

typedef float floatx2 __attribute__((ext_vector_type(2)));

// ---------------- f32 -> fp8 e4m3 weight conversion (streaming) -------------
// 16 elems / thread / iter: 4x float4 in, 1x uint4 out. Weights scaled by 64
// before packing (HW v_cvt_pk_fp8_f32, RNE).
__global__ __launch_bounds__(256) void convert_weight_fp8(
    const float* __restrict__ w, uint4* __restrict__ wq)
{
    const int total16 = V * EDIM / 16;   // 3,216,448
    int i = blockIdx.x * blockDim.x + threadIdx.x;
    const int stride = gridDim.x * blockDim.x;
    for (; i < total16; i += stride) {
        const float4* p = (const float4*)w + 4 * (size_t)i;
        float4 a0 = p[0], a1 = p[1], a2 = p[2], a3 = p[3];
        uint4 o;
        int d;
        d = 0;
        d = __builtin_amdgcn_cvt_pk_fp8_f32(a0.x * WSCALE, a0.y * WSCALE, d, false);
        d = __builtin_amdgcn_cvt_pk_fp8_f32(a0.z * WSCALE, a0.w * WSCALE, d, true);
        o.x = (unsigned int)d;
        d = 0;
        d = __builtin_amdgcn_cvt_pk_fp8_f32(a1.x * WSCALE, a1.y * WSCALE, d, false);
        d = __builtin_amdgcn_cvt_pk_fp8_f32(a1.z * WSCALE, a1.w * WSCALE, d, true);
        o.y = (unsigned int)d;
        d = 0;
        d = __builtin_amdgcn_cvt_pk_fp8_f32(a2.x * WSCALE, a2.y * WSCALE, d, false);
        d = __builtin_amdgcn_cvt_pk_fp8_f32(a2.z * WSCALE, a2.w * WSCALE, d, true);
        o.z = (unsigned int)d;
        d = 0;
        d = __builtin_amdgcn_cvt_pk_fp8_f32(a3.x * WSCALE, a3.y * WSCALE, d, false);
        d = __builtin_amdgcn_cvt_pk_fp8_f32(a3.z * WSCALE, a3.w * WSCALE, d, true);
        o.w = (unsigned int)d;
        wq[i] = o;
    }
}

// ---------------- fp8 gather main kernel ------------------------------------
// One block per row n, 4 waves. Wave w owns k in [13w, 13w+13) (k=51 masked
// dup). fp8 row = 1 KB -> exactly ONE dwordx4 per lane per gathered row;
// all 13 row loads issued back-to-back (13 KB/wave in flight), indices in
// SGPRs via readfirstlane, all reductions + transcendentals deferred.
__global__ __launch_bounds__(256) void nce_main_q(
    const float* __restrict__ input,
    const int*   __restrict__ target,
    const int*   __restrict__ noise_samples,
    const float* __restrict__ noise,
    const unsigned char* __restrict__ wq,
    const float* __restrict__ bias,
    float*       __restrict__ partial)
{
    const int n    = blockIdx.x;
    const int tid  = threadIdx.x;
    const int wave = tid >> 6;
    const int lane = tid & 63;

    // lane's input fragment: elems [16*lane, 16*lane+16)
    const float4* inrow = (const float4*)(input + (size_t)n * EDIM);
    float4 inf[4];
#pragma unroll
    for (int p = 0; p < 4; ++p)
        inf[p] = inrow[4 * lane + p];

    const int start = wave * RPW;

    // resolve all gather indices up front (uniform -> SGPR)
    int idx[RPW];
#pragma unroll
    for (int j = 0; j < RPW; ++j) {
        const int kk = start + j;
        const int kc = (kk < KTOT) ? kk : start;          // pad: dup row, masked later
        int v = (kc == 0) ? target[n] : noise_samples[n * KNOISE + kc - 1];
        idx[j] = __builtin_amdgcn_readfirstlane(v);
    }

    // issue all 13 row loads (one dwordx4 each)
    uint4 c[RPW];
#pragma unroll
    for (int j = 0; j < RPW; ++j)
        c[j] = ((const uint4*)(wq + (size_t)idx[j] * EDIM))[lane];

    // unpack (HW fp8->f32) + FMA
    float dot[RPW];
#pragma unroll
    for (int j = 0; j < RPW; ++j) dot[j] = 0.0f;
#pragma unroll
    for (int j = 0; j < RPW; ++j) {
        const unsigned int wd[4] = { c[j].x, c[j].y, c[j].z, c[j].w };
#pragma unroll
        for (int d = 0; d < 4; ++d) {
            const floatx2 f0 = __builtin_amdgcn_cvt_pk_f32_fp8((int)wd[d], false);
            const floatx2 f1 = __builtin_amdgcn_cvt_pk_f32_fp8((int)wd[d], true);
            const float4 x = inf[d];
            dot[j] = fmaf(x.x, f0.x, dot[j]);
            dot[j] = fmaf(x.y, f0.y, dot[j]);
            dot[j] = fmaf(x.z, f1.x, dot[j]);
            dot[j] = fmaf(x.w, f1.y, dot[j]);
        }
    }

    // deferred reductions: 13 interleaved butterflies
#pragma unroll
    for (int off = 32; off > 0; off >>= 1) {
#pragma unroll
        for (int j = 0; j < RPW; ++j)
            dot[j] += __shfl_xor(dot[j], off, 64);
    }

    // deferred term math (uniform across lanes; scalar loads off SGPR idx)
    float acc = 0.0f;
#pragma unroll
    for (int j = 0; j < RPW; ++j) {
        const int kk = start + j;
        if (kk < KTOT) {                                   // wave-uniform guard
            const float bz = bias[idx[j]];
            const float cz = (float)KNOISE * noise[idx[j]];
            const float p  = __expf(dot[j] * INV_WSCALE + bz - NORM_TERM);
            const float num = (kk == 0) ? p : cz;
            acc += __logf(num / (p + cz));
        }
    }

    __shared__ float warr[4];
    if (lane == 0) warr[wave] = acc;
    __syncthreads();
    if (tid == 0) {
        const float s = warr[0] + warr[1] + warr[2] + warr[3];
        atomicAdd(&partial[n & (NSLOTS - 1)], -s * (1.0f / (float)NROWS));
    }
}

// ---------------- f32 fallback (R2 structure) if ws too small ---------------
__global__ __launch_bounds__(256) void nce_main_f32(
    const float* __restrict__ input,
    const int*   __restrict__ target,
    const int*   __restrict__ noise_samples,
    const float* __restrict__ noise,
    const float* __restrict__ weight,
    const float* __restrict__ bias,
    float*       __restrict__ partial)
{
    const int n    = blockIdx.x;
    const int tid  = threadIdx.x;
    const int wave = tid >> 6;
    const int lane = tid & 63;

    const float4* inrow = (const float4*)(input + (size_t)n * EDIM);
    float4 inv[4];
#pragma unroll
    for (int p = 0; p < 4; ++p)
        inv[p] = inrow[p * 64 + lane];

    const int start = wave * RPW;
    const int end   = (start + RPW < KTOT) ? start + RPW : KTOT;

    float acc = 0.0f;
    int k = start;
    for (; k + 4 <= end; k += 4) {
        int idx[4];
#pragma unroll
        for (int i = 0; i < 4; ++i) {
            const int kk = k + i;
            idx[i] = (kk == 0) ? target[n] : noise_samples[n * KNOISE + kk - 1];
        }
        float bz[4], cz[4];
#pragma unroll
        for (int i = 0; i < 4; ++i) {
            bz[i] = bias[idx[i]];
            cz[i] = (float)KNOISE * noise[idx[i]];
        }
        float4 wr[4][4];
#pragma unroll
        for (int i = 0; i < 4; ++i) {
            const float4* wrow = (const float4*)(weight + (size_t)idx[i] * EDIM);
#pragma unroll
            for (int p = 0; p < 4; ++p)
                wr[i][p] = wrow[p * 64 + lane];
        }
        float dot[4] = {0.f, 0.f, 0.f, 0.f};
#pragma unroll
        for (int i = 0; i < 4; ++i) {
#pragma unroll
            for (int p = 0; p < 4; ++p) {
                dot[i] = fmaf(inv[p].x, wr[i][p].x, dot[i]);
                dot[i] = fmaf(inv[p].y, wr[i][p].y, dot[i]);
                dot[i] = fmaf(inv[p].z, wr[i][p].z, dot[i]);
                dot[i] = fmaf(inv[p].w, wr[i][p].w, dot[i]);
            }
        }
#pragma unroll
        for (int off = 32; off > 0; off >>= 1) {
#pragma unroll
            for (int i = 0; i < 4; ++i)
                dot[i] += __shfl_xor(dot[i], off, 64);
        }
#pragma unroll
        for (int i = 0; i < 4; ++i) {
            const float p   = __expf(dot[i] + bz[i] - NORM_TERM);
            const float num = (k + i == 0) ? p : cz[i];
            acc += __logf(num / (p + cz[i]));
        }
    }
    for (; k < end; ++k) {
        const int idx = (k == 0) ? target[n] : noise_samples[n * KNOISE + k - 1];
        const float bz = bias[idx];
        const float cz = (float)KNOISE * noise[idx];
        const float4* wrow = (const float4*)(weight + (size_t)idx * EDIM);
        float dot = 0.f;
#pragma unroll
        for (int p = 0; p < 4; ++p) {
            float4 w = wrow[p * 64 + lane];
            dot = fmaf(inv[p].x, w.x, dot);
            dot = fmaf(inv[p].y, w.y, dot);
            dot = fmaf(inv[p].z, w.z, dot);
            dot = fmaf(inv[p].w, w.w, dot);
        }
#pragma unroll
        for (int off = 32; off > 0; off >>= 1)
            dot += __shfl_xor(dot, off, 64);
        const float p   = __expf(dot + bz - NORM_TERM);
        const float num = (k == 0) ? p : cz;
        acc += __logf(num / (p + cz));
    }

    __shared__ float warr[4];
    if (lane == 0) warr[wave] = acc;
    __syncthreads();
    if (tid == 0) {
        const float s = warr[0] + warr[1] + warr[2] + warr[3];
        atomicAdd(&partial[n & (NSLOTS - 1)], -s * (1.0f / (float)NROWS));
    }
}

__global__ __launch_bounds__(64) void nce_finish(const float* __restrict__ partial,
                                                 float* __restrict__ out)
{
    const int lane = threadIdx.x;
    float v = partial[lane] + partial[lane + 64] + partial[lane + 128] + partial[lane + 192];
#pragma unroll
    for (int off = 32; off > 0; off >>= 1)
        v += __shfl_xor(v, off, 64);
    if (lane == 0) out[0] = v;
}

extern "C" void kernel_launch(void* const* d_in, const int* in_sizes, int n_in,
                              void* d_out, int out_size, void* d_ws, size_t ws_size,
                              hipStream_t stream) {
    const float* input         = (const float*)d_in[0];
    const int*   target        = (const int*)  d_in[1];
    const int*   noise_samples = (const int*)  d_in[2];
    const float* noise         = (const float*)d_in[3];
    const float* weight        = (const float*)d_in[4];
    const float* bias          = (const float*)d_in[5];
    float*       out           = (float*)d_out;
    float*       partial       = (float*)d_ws;   // 256 f32 slots at ws[0]

    hipMemsetAsync(partial, 0, NSLOTS * sizeof(float), stream);

    const size_t need = 1024 + (size_t)V * EDIM;  // ~51.5 MB fp8 table
    if (ws_size >= need) {
        unsigned char* wq = (unsigned char*)d_ws + 1024;
        convert_weight_fp8<<<4096, 256, 0, stream>>>(weight, (uint4*)wq);
        nce_main_q<<<NROWS, 256, 0, stream>>>(
            input, target, noise_samples, noise, wq, bias, partial);
    } else {
        nce_main_f32<<<NROWS, 256, 0, stream>>>(
            input, target, noise_samples, noise, weight, bias, partial);
    }
    nce_finish<<<1, 64, 0, stream>>>(partial, out);
}